// Round 16
// baseline (233.660 us; speedup 1.0000x reference)
//
#include <hip/hip_runtime.h>
#include <stdint.h>

// ---------- problem constants ----------
#define B_DIM 2
#define T_DIM 4096
#define C_DIM 512
#define H_DIM 8
#define D_DIM 64
#define M_DIM (B_DIM * T_DIM)   // 8192

typedef __attribute__((ext_vector_type(8))) short bf16x8;   // MFMA A/B frag (8 bf16)
typedef __attribute__((ext_vector_type(4))) float f32x4;    // MFMA C/D frag
typedef __attribute__((ext_vector_type(4))) short short4v;  // 8B vector

__device__ inline unsigned short f2bf(float f) {
    union { float f; uint32_t u; } v; v.f = f;
    uint32_t r = v.u + 0x7fffu + ((v.u >> 16) & 1u);   // RNE
    return (unsigned short)(r >> 16);
}

__device__ inline uint32_t cvtpk(float a, float b) {
    uint32_t r;
    asm("v_cvt_pk_bf16_f32 %0, %1, %2" : "=v"(r) : "v"(a), "v"(b));
    return r;
}

__device__ inline float fexp2(float x) {
    float r;
    asm("v_exp_f32 %0, %1" : "=v"(r) : "v"(x));
    return r;
}

__device__ inline float bf2f(unsigned short u) {
    union { uint32_t u; float f; } v; v.u = (uint32_t)u << 16; return v.f;
}

// ---------- f32 -> bf16 conversion (x) ----------
__global__ __launch_bounds__(256) void cvt_kernel(const float* __restrict__ in,
                                                  unsigned short* __restrict__ out, int n) {
    int i = (blockIdx.x * 256 + threadIdx.x) * 4;
    if (i >= n) return;
    float4 v = *(const float4*)(in + i);
    uint2 o;
    o.x = cvtpk(v.x, v.y);
    o.y = cvtpk(v.z, v.w);
    *(uint2*)(out + i) = o;
}

// ---------- batched f32 -> bf16 for the 4 weight matrices ----------
__global__ __launch_bounds__(256) void cvt_w_kernel(const float* __restrict__ Wq,
                                                    const float* __restrict__ Wk,
                                                    const float* __restrict__ Wv,
                                                    const float* __restrict__ Wo,
                                                    unsigned short* __restrict__ out) {
    const int widx = blockIdx.x >> 8;
    const float* src = (widx == 0) ? Wq : (widx == 1) ? Wk : (widx == 2) ? Wv : Wo;
    const int i = ((blockIdx.x & 255) * 256 + threadIdx.x) * 4;
    float4 v = *(const float4*)(src + i);
    uint2 o;
    o.x = cvtpk(v.x, v.y);
    o.y = cvtpk(v.z, v.w);
    *(uint2*)(out + (size_t)widx * C_DIM * C_DIM + i) = o;
}

// ---------- fused Q/K/V GEMM (unchanged, proven) ----------
__global__ __launch_bounds__(256) void gemm_qkv(const unsigned short* __restrict__ A,
                                                const unsigned short* __restrict__ Wb,
                                                unsigned short* __restrict__ Qh,
                                                unsigned short* __restrict__ Kh,
                                                unsigned short* __restrict__ Vt) {
    const int wave = threadIdx.x >> 6;
    const int lane = threadIdx.x & 63;
    const int g    = lane >> 4;
    const int lr   = lane & 15;
    const int row0 = blockIdx.x * 128 + wave * 32;
    const int col0 = blockIdx.y * 128;
    const int z    = blockIdx.z;
    const unsigned short* W = Wb + (size_t)z * C_DIM * C_DIM;

    f32x4 acc[2][8];
#pragma unroll
    for (int r = 0; r < 2; ++r)
#pragma unroll
        for (int i = 0; i < 8; ++i) acc[r][i] = (f32x4){0.f, 0.f, 0.f, 0.f};

    const unsigned short* Arow0 = A + (size_t)(row0 + lr) * C_DIM;
    const unsigned short* Arow1 = A + (size_t)(row0 + 16 + lr) * C_DIM;
#pragma unroll 2
    for (int kk = 0; kk < C_DIM; kk += 32) {
        bf16x8 a0 = *(const bf16x8*)(Arow0 + kk + g * 8);
        bf16x8 a1 = *(const bf16x8*)(Arow1 + kk + g * 8);
#pragma unroll
        for (int nt = 0; nt < 8; ++nt) {
            const unsigned short* Wrow = W + (size_t)(col0 + nt * 16 + lr) * C_DIM;
            bf16x8 b = *(const bf16x8*)(Wrow + kk + g * 8);
            acc[0][nt] = __builtin_amdgcn_mfma_f32_16x16x32_bf16(a0, b, acc[0][nt], 0, 0, 0);
            acc[1][nt] = __builtin_amdgcn_mfma_f32_16x16x32_bf16(a1, b, acc[1][nt], 0, 0, 0);
        }
    }

    unsigned short* Oqk = (z == 0) ? Qh : Kh;
#pragma unroll
    for (int ar = 0; ar < 2; ++ar) {
        const int rowb = row0 + ar * 16;
#pragma unroll
        for (int nt = 0; nt < 8; ++nt) {
            const int n = col0 + nt * 16 + lr;
            const int h = n >> 6, d = n & 63;
            if (z < 2) {
#pragma unroll
                for (int j = 0; j < 4; ++j) {
                    int m = rowb + g * 4 + j;
                    int b = m >> 12, t = m & (T_DIM - 1);
                    Oqk[((size_t)(b * H_DIM + h) * T_DIM + t) * D_DIM + d] = f2bf(acc[ar][nt][j]);
                }
            } else {
                int m = rowb + g * 4;
                int b = m >> 12, t = m & (T_DIM - 1);
                int tp = (t & ~31) | (((t >> 2) & 3) << 3) | (((t >> 4) & 1) << 2);
                short4v pack;
#pragma unroll
                for (int j = 0; j < 4; ++j) pack[j] = (short)f2bf(acc[ar][nt][j]);
                *(short4v*)(Vt + ((size_t)(b * H_DIM + h) * D_DIM + d) * T_DIM + tp) = pack;
            }
        }
    }
}

// ---------- output GEMM (f32 out), 128x128 tile (unchanged) ----------
__global__ __launch_bounds__(256) void gemm_out(const unsigned short* __restrict__ A,
                                                const unsigned short* __restrict__ W,
                                                float* __restrict__ O) {
    const int wave = threadIdx.x >> 6;
    const int lane = threadIdx.x & 63;
    const int g    = lane >> 4;
    const int lr   = lane & 15;
    const int row0 = blockIdx.x * 128 + wave * 32;
    const int col0 = blockIdx.y * 128;

    f32x4 acc[2][8];
#pragma unroll
    for (int r = 0; r < 2; ++r)
#pragma unroll
        for (int i = 0; i < 8; ++i) acc[r][i] = (f32x4){0.f, 0.f, 0.f, 0.f};

    const unsigned short* Arow0 = A + (size_t)(row0 + lr) * C_DIM;
    const unsigned short* Arow1 = A + (size_t)(row0 + 16 + lr) * C_DIM;
#pragma unroll 2
    for (int kk = 0; kk < C_DIM; kk += 32) {
        bf16x8 a0 = *(const bf16x8*)(Arow0 + kk + g * 8);
        bf16x8 a1 = *(const bf16x8*)(Arow1 + kk + g * 8);
#pragma unroll
        for (int nt = 0; nt < 8; ++nt) {
            const unsigned short* Wrow = W + (size_t)(col0 + nt * 16 + lr) * C_DIM;
            bf16x8 b = *(const bf16x8*)(Wrow + kk + g * 8);
            acc[0][nt] = __builtin_amdgcn_mfma_f32_16x16x32_bf16(a0, b, acc[0][nt], 0, 0, 0);
            acc[1][nt] = __builtin_amdgcn_mfma_f32_16x16x32_bf16(a1, b, acc[1][nt], 0, 0, 0);
        }
    }

#pragma unroll
    for (int ar = 0; ar < 2; ++ar) {
        const int rowb = row0 + ar * 16;
#pragma unroll
        for (int nt = 0; nt < 8; ++nt) {
            const int n = col0 + nt * 16 + lr;
#pragma unroll
            for (int j = 0; j < 4; ++j) {
                int m = rowb + g * 4 + j;
                O[(size_t)m * C_DIM + n] = acc[ar][nt][j];
            }
        }
    }
}

// ---------- split-K causal flash attention ----------
// r14+r15 analysis: per-slot cost halves at 4 waves/SIMD (2600cy vs 5000cy) but
// r14's static grid wasted it on CU imbalance. Fixed-m softmax => partials are
// PLAIN SUMS, so kv can split across BLOCKS: 2048 uniform blocks = (head, pair
// (ord,127-ord), half). Slot s = 2*half+wave takes kv64-units s, s+4, s+8,...
// -> every wave ~16.25 units, perfect balance at 8 blocks/CU = 4 waves/SIMD.
// Blocks write unnormalized partials (O bf16, l f32); attn_merge sums halves,
// normalizes, writes attnb. Body = r14's proven VGPR-100 loop (one tile live).
__global__ __launch_bounds__(128, 2) void attn_split(const unsigned short* __restrict__ Qh,
                                                     const unsigned short* __restrict__ Kh,
                                                     const unsigned short* __restrict__ Vt,
                                                     unsigned short* __restrict__ pO,
                                                     float* __restrict__ pl) {
    const int wave = threadIdx.x >> 6;
    const int lane = threadIdx.x & 63;
    const int g    = lane >> 4;
    const int lr   = lane & 15;
    const int bid  = blockIdx.x;
    const int bh   = bid & 15;
    const int ord  = (bid >> 4) & 63;
    const int half = bid >> 10;          // 0 or 1

    const unsigned short* Qp = Qh + (size_t)bh * T_DIM * D_DIM;
    const unsigned short* Kp = Kh + (size_t)bh * T_DIM * D_DIM;
    const unsigned short* Vp = Vt + (size_t)bh * D_DIM * T_DIM;

    const float KC = 0.125f * 1.44269504f;   // scale * log2(e)

    __shared__ float lds_o[2][64][17];       // [h][lane][16 elems + pad]
    __shared__ float lds_l[2][16];

#pragma unroll 1
    for (int t = 0; t < 2; ++t) {
        const int qb = t ? (127 - ord) : ord;
        const int qw = qb * 32;
        const int kvend = qw + 32;

        bf16x8 qf[2][2];
#pragma unroll
        for (int h = 0; h < 2; ++h)
#pragma unroll
            for (int dh = 0; dh < 2; ++dh)
                qf[h][dh] = *(const bf16x8*)(Qp + (size_t)(qw + h * 16 + lr) * D_DIM + dh * 32 + g * 8);

        f32x4 oacc[2][4];
        float lR[2] = {0.f, 0.f};
#pragma unroll
        for (int h = 0; h < 2; ++h)
#pragma unroll
            for (int d0 = 0; d0 < 4; ++d0) oacc[h][d0] = (f32x4){0.f, 0.f, 0.f, 0.f};

        const int kvstart = (2 * half + wave) * 64;
        bf16x8 kc8[4][2];
#pragma unroll
        for (int i = 0; i < 4; ++i)
#pragma unroll
            for (int dh = 0; dh < 2; ++dh)
                kc8[i][dh] = *(const bf16x8*)(Kp + (size_t)(kvstart + i * 16 + lr) * D_DIM + dh * 32 + g * 8);

        for (int kv0 = kvstart; kv0 < kvend; kv0 += 256) {
            const int kvn = (kv0 + 256 < kvend) ? kv0 + 256 : kvstart;
            bf16x8 kn8[4][2];
#pragma unroll
            for (int i = 0; i < 4; ++i)
#pragma unroll
                for (int dh = 0; dh < 2; ++dh)
                    kn8[i][dh] = *(const bf16x8*)(Kp + (size_t)(kvn + i * 16 + lr) * D_DIM + dh * 32 + g * 8);

            bf16x8 vf[2][4];
#pragma unroll
            for (int kh = 0; kh < 2; ++kh)
#pragma unroll
                for (int d0 = 0; d0 < 4; ++d0)
                    vf[kh][d0] = *(const bf16x8*)(Vp + (size_t)(d0 * 16 + lr) * T_DIM + kv0 + kh * 32 + g * 8);

            f32x4 s[2][4];
#pragma unroll
            for (int h = 0; h < 2; ++h)
#pragma unroll
                for (int i = 0; i < 4; ++i) s[h][i] = (f32x4){0.f, 0.f, 0.f, 0.f};
#pragma unroll
            for (int i = 0; i < 4; ++i) {
                s[0][i] = __builtin_amdgcn_mfma_f32_16x16x32_bf16(kc8[i][0], qf[0][0], s[0][i], 0, 0, 0);
                s[0][i] = __builtin_amdgcn_mfma_f32_16x16x32_bf16(kc8[i][1], qf[0][1], s[0][i], 0, 0, 0);
                s[1][i] = __builtin_amdgcn_mfma_f32_16x16x32_bf16(kc8[i][0], qf[1][0], s[1][i], 0, 0, 0);
                s[1][i] = __builtin_amdgcn_mfma_f32_16x16x32_bf16(kc8[i][1], qf[1][1], s[1][i], 0, 0, 0);
            }

            const bool maskit = (kv0 + 63 > qw);

#pragma unroll
            for (int h = 0; h < 2; ++h) {
                const int qh = qw + h * 16 + lr;
                float p[16];
                if (maskit) {
#pragma unroll
                    for (int i = 0; i < 4; ++i)
#pragma unroll
                        for (int j = 0; j < 4; ++j) {
                            int kva = kv0 + i * 16 + g * 4 + j;
                            float zz = (kva > qh) ? -1e30f : s[h][i][j];
                            p[i * 4 + j] = fexp2(zz * KC);   // masked -> 0
                        }
                } else {
#pragma unroll
                    for (int i = 0; i < 4; ++i)
#pragma unroll
                        for (int j = 0; j < 4; ++j)
                            p[i * 4 + j] = fexp2(s[h][i][j] * KC);
                }

                lR[h] += ((p[0] + p[1]) + (p[2] + p[3])) + ((p[4] + p[5]) + (p[6] + p[7]))
                       + ((p[8] + p[9]) + (p[10] + p[11])) + ((p[12] + p[13]) + (p[14] + p[15]));

                union { bf16x8 v; uint32_t w[4]; } pf0, pf1;
#pragma unroll
                for (int w = 0; w < 4; ++w) pf0.w[w] = cvtpk(p[2 * w], p[2 * w + 1]);
#pragma unroll
                for (int w = 0; w < 4; ++w) pf1.w[w] = cvtpk(p[8 + 2 * w], p[9 + 2 * w]);

#pragma unroll
                for (int d0 = 0; d0 < 4; ++d0)
                    oacc[h][d0] = __builtin_amdgcn_mfma_f32_16x16x32_bf16(vf[0][d0], pf0.v, oacc[h][d0], 0, 0, 0);
#pragma unroll
                for (int d0 = 0; d0 < 4; ++d0)
                    oacc[h][d0] = __builtin_amdgcn_mfma_f32_16x16x32_bf16(vf[1][d0], pf1.v, oacc[h][d0], 0, 0, 0);
            }

#pragma unroll
            for (int i = 0; i < 4; ++i)
#pragma unroll
                for (int dh = 0; dh < 2; ++dh) kc8[i][dh] = kn8[i][dh];
        }

        // cross-lane l reduction
#pragma unroll
        for (int h = 0; h < 2; ++h) {
            lR[h] += __shfl_xor(lR[h], 16);
            lR[h] += __shfl_xor(lR[h], 32);
        }

        // wave 1 publishes; wave 0 merges and writes this half's partials
        if (wave == 1) {
#pragma unroll
            for (int h = 0; h < 2; ++h) {
#pragma unroll
                for (int d0 = 0; d0 < 4; ++d0)
#pragma unroll
                    for (int j = 0; j < 4; ++j)
                        lds_o[h][lane][d0 * 4 + j] = oacc[h][d0][j];
                if (g == 0) lds_l[h][lr] = lR[h];
            }
        }
        __syncthreads();

        if (wave == 0) {
            const size_t hb = ((size_t)(half * 16 + bh)) * T_DIM;
#pragma unroll
            for (int h = 0; h < 2; ++h) {
                const int row = qw + h * 16 + lr;
                unsigned short* orow = pO + (hb + row) * D_DIM;
#pragma unroll
                for (int d0 = 0; d0 < 4; ++d0) {
                    float e0 = oacc[h][d0][0] + lds_o[h][lane][d0 * 4 + 0];
                    float e1 = oacc[h][d0][1] + lds_o[h][lane][d0 * 4 + 1];
                    float e2 = oacc[h][d0][2] + lds_o[h][lane][d0 * 4 + 2];
                    float e3 = oacc[h][d0][3] + lds_o[h][lane][d0 * 4 + 3];
                    uint2 st;
                    st.x = cvtpk(e0, e1);
                    st.y = cvtpk(e2, e3);
                    *(uint2*)(orow + d0 * 16 + g * 4) = st;
                }
                if (g == 0) pl[hb + row] = lR[h] + lds_l[h][lr];
            }
        }
        __syncthreads();   // LDS reuse before next tile
    }
}

// ---------- merge halves, normalize, write attnb ----------
__global__ __launch_bounds__(256) void attn_merge(const unsigned short* __restrict__ pO,
                                                  const float* __restrict__ pl,
                                                  unsigned short* __restrict__ attnb) {
    const int c = blockIdx.x * 256 + threadIdx.x;   // chunk of 8 bf16
    const int row = c >> 3;                          // 0..65535 = bh*4096 + r
    const int d = (c & 7) * 8;
    const int bh = row >> 12, r = row & 4095;
    const size_t HS = (size_t)16 * T_DIM * D_DIM;    // elems per half

    const size_t pbase = (size_t)row * D_DIM + d;
    bf16x8 a = *(const bf16x8*)(pO + pbase);
    bf16x8 b = *(const bf16x8*)(pO + HS + pbase);
    const float inv = 1.0f / (pl[row] + pl[(HS / D_DIM) + row]);

    union { bf16x8 v; uint32_t w[4]; } o;
#pragma unroll
    for (int i = 0; i < 4; ++i) {
        float e0 = (bf2f((unsigned short)a[2 * i])     + bf2f((unsigned short)b[2 * i]))     * inv;
        float e1 = (bf2f((unsigned short)a[2 * i + 1]) + bf2f((unsigned short)b[2 * i + 1])) * inv;
        o.w[i] = cvtpk(e0, e1);
    }
    const int bb = bh >> 3, hh = bh & 7;
    *(bf16x8*)(attnb + ((size_t)(bb * T_DIM + r)) * C_DIM + hh * D_DIM + d) = o.v;
}

// ---------- fallback attention (r15, proven 139us) ----------
__global__ __launch_bounds__(128, 2) void attn_fb(const unsigned short* __restrict__ Qh,
                                                  const unsigned short* __restrict__ Kh,
                                                  const unsigned short* __restrict__ Vt,
                                                  unsigned short* __restrict__ attn) {
    const int wave = threadIdx.x >> 6;
    const int lane = threadIdx.x & 63;
    const int g    = lane >> 4;
    const int lr   = lane & 15;
    const int bid  = blockIdx.x;
    const int bh   = bid & 15;
    const int qb   = 127 - (bid >> 4);
    const int qw   = qb * 32;
    const int kvend = qw + 32;

    const unsigned short* Qp = Qh + (size_t)bh * T_DIM * D_DIM;
    const unsigned short* Kp = Kh + (size_t)bh * T_DIM * D_DIM;
    const unsigned short* Vp = Vt + (size_t)bh * D_DIM * T_DIM;
    const float KC = 0.125f * 1.44269504f;

    __shared__ float lds_o[2][64][17];
    __shared__ float lds_l[2][16];

    bf16x8 qf[2][2];
#pragma unroll
    for (int h = 0; h < 2; ++h)
#pragma unroll
        for (int dh = 0; dh < 2; ++dh)
            qf[h][dh] = *(const bf16x8*)(Qp + (size_t)(qw + h * 16 + lr) * D_DIM + dh * 32 + g * 8);

    f32x4 oacc[2][4];
    float lR[2] = {0.f, 0.f};
#pragma unroll
    for (int h = 0; h < 2; ++h)
#pragma unroll
        for (int d0 = 0; d0 < 4; ++d0) oacc[h][d0] = (f32x4){0.f, 0.f, 0.f, 0.f};

    const int kvstart = wave * 64;
    bf16x8 kc8[4][2];
#pragma unroll
    for (int i = 0; i < 4; ++i)
#pragma unroll
        for (int dh = 0; dh < 2; ++dh)
            kc8[i][dh] = *(const bf16x8*)(Kp + (size_t)(kvstart + i * 16 + lr) * D_DIM + dh * 32 + g * 8);

    for (int kv0 = kvstart; kv0 < kvend; kv0 += 128) {
        const int kvn = (kv0 + 128 < kvend) ? kv0 + 128 : kvstart;
        bf16x8 kn8[4][2];
#pragma unroll
        for (int i = 0; i < 4; ++i)
#pragma unroll
            for (int dh = 0; dh < 2; ++dh)
                kn8[i][dh] = *(const bf16x8*)(Kp + (size_t)(kvn + i * 16 + lr) * D_DIM + dh * 32 + g * 8);

        bf16x8 vf[2][4];
#pragma unroll
        for (int kh = 0; kh < 2; ++kh)
#pragma unroll
            for (int d0 = 0; d0 < 4; ++d0)
                vf[kh][d0] = *(const bf16x8*)(Vp + (size_t)(d0 * 16 + lr) * T_DIM + kv0 + kh * 32 + g * 8);

        f32x4 s[2][4];
#pragma unroll
        for (int h = 0; h < 2; ++h)
#pragma unroll
            for (int i = 0; i < 4; ++i) s[h][i] = (f32x4){0.f, 0.f, 0.f, 0.f};
#pragma unroll
        for (int i = 0; i < 4; ++i) {
            s[0][i] = __builtin_amdgcn_mfma_f32_16x16x32_bf16(kc8[i][0], qf[0][0], s[0][i], 0, 0, 0);
            s[0][i] = __builtin_amdgcn_mfma_f32_16x16x32_bf16(kc8[i][1], qf[0][1], s[0][i], 0, 0, 0);
            s[1][i] = __builtin_amdgcn_mfma_f32_16x16x32_bf16(kc8[i][0], qf[1][0], s[1][i], 0, 0, 0);
            s[1][i] = __builtin_amdgcn_mfma_f32_16x16x32_bf16(kc8[i][1], qf[1][1], s[1][i], 0, 0, 0);
        }

        const bool maskit = (kv0 + 63 > qw);
#pragma unroll
        for (int h = 0; h < 2; ++h) {
            const int qh = qw + h * 16 + lr;
            float p[16];
            if (maskit) {
#pragma unroll
                for (int i = 0; i < 4; ++i)
#pragma unroll
                    for (int j = 0; j < 4; ++j) {
                        int kva = kv0 + i * 16 + g * 4 + j;
                        float zz = (kva > qh) ? -1e30f : s[h][i][j];
                        p[i * 4 + j] = fexp2(zz * KC);
                    }
            } else {
#pragma unroll
                for (int i = 0; i < 4; ++i)
#pragma unroll
                    for (int j = 0; j < 4; ++j)
                        p[i * 4 + j] = fexp2(s[h][i][j] * KC);
            }
            lR[h] += ((p[0] + p[1]) + (p[2] + p[3])) + ((p[4] + p[5]) + (p[6] + p[7]))
                   + ((p[8] + p[9]) + (p[10] + p[11])) + ((p[12] + p[13]) + (p[14] + p[15]));

            union { bf16x8 v; uint32_t w[4]; } pf0, pf1;
#pragma unroll
            for (int w = 0; w < 4; ++w) pf0.w[w] = cvtpk(p[2 * w], p[2 * w + 1]);
#pragma unroll
            for (int w = 0; w < 4; ++w) pf1.w[w] = cvtpk(p[8 + 2 * w], p[9 + 2 * w]);
#pragma unroll
            for (int d0 = 0; d0 < 4; ++d0)
                oacc[h][d0] = __builtin_amdgcn_mfma_f32_16x16x32_bf16(vf[0][d0], pf0.v, oacc[h][d0], 0, 0, 0);
#pragma unroll
            for (int d0 = 0; d0 < 4; ++d0)
                oacc[h][d0] = __builtin_amdgcn_mfma_f32_16x16x32_bf16(vf[1][d0], pf1.v, oacc[h][d0], 0, 0, 0);
        }
#pragma unroll
        for (int i = 0; i < 4; ++i)
#pragma unroll
            for (int dh = 0; dh < 2; ++dh) kc8[i][dh] = kn8[i][dh];
    }

#pragma unroll
    for (int h = 0; h < 2; ++h) {
        lR[h] += __shfl_xor(lR[h], 16);
        lR[h] += __shfl_xor(lR[h], 32);
    }
    if (wave == 1) {
#pragma unroll
        for (int h = 0; h < 2; ++h) {
#pragma unroll
            for (int d0 = 0; d0 < 4; ++d0)
#pragma unroll
                for (int j = 0; j < 4; ++j)
                    lds_o[h][lane][d0 * 4 + j] = oacc[h][d0][j];
            if (g == 0) lds_l[h][lr] = lR[h];
        }
    }
    __syncthreads();
    if (wave == 0) {
        const int b = bh >> 3, hh = bh & 7;
#pragma unroll
        for (int h = 0; h < 2; ++h) {
            const float linv = 1.0f / (lR[h] + lds_l[h][lr]);
            unsigned short* orow = attn + ((size_t)(b * T_DIM + qw + h * 16 + lr)) * C_DIM + hh * D_DIM;
#pragma unroll
            for (int d0 = 0; d0 < 4; ++d0) {
                float e0 = (oacc[h][d0][0] + lds_o[h][lane][d0 * 4 + 0]) * linv;
                float e1 = (oacc[h][d0][1] + lds_o[h][lane][d0 * 4 + 1]) * linv;
                float e2 = (oacc[h][d0][2] + lds_o[h][lane][d0 * 4 + 2]) * linv;
                float e3 = (oacc[h][d0][3] + lds_o[h][lane][d0 * 4 + 3]) * linv;
                uint2 st;
                st.x = cvtpk(e0, e1);
                st.y = cvtpk(e2, e3);
                *(uint2*)(orow + d0 * 16 + g * 4) = st;
            }
        }
    }
}

// ---------- launch ----------
extern "C" void kernel_launch(void* const* d_in, const int* in_sizes, int n_in,
                              void* d_out, int out_size, void* d_ws, size_t ws_size,
                              hipStream_t stream) {
    const float* x  = (const float*)d_in[0];
    const float* Wq = (const float*)d_in[1];
    const float* Wk = (const float*)d_in[2];
    const float* Wv = (const float*)d_in[3];
    const float* Wo = (const float*)d_in[4];

    char* ws = (char*)d_ws;
    unsigned short* xb    = (unsigned short*)(ws + 0);         //  8.4 MB
    unsigned short* Wb    = (unsigned short*)(ws + 8388608);   //  2 MB
    unsigned short* Qh    = (unsigned short*)(ws + 10485760);  //  8.4 MB
    unsigned short* Kh    = (unsigned short*)(ws + 18874368);  //  8.4 MB
    unsigned short* Vt    = (unsigned short*)(ws + 27262976);  //  8.4 MB
    unsigned short* attnb = (unsigned short*)(ws + 35651584);  //  8.4 MB
    unsigned short* pO    = (unsigned short*)(ws + 44040192);  // 16.8 MB [2][16][4096][64] bf16
    float*          pl    = (float*)         (ws + 60817408);  //  0.5 MB [2][16][4096] f32
    const size_t NEED = 61341696;

    const int nX = M_DIM * C_DIM;

    cvt_kernel<<<nX / 4 / 256, 256, 0, stream>>>(x, xb, nX);
    cvt_w_kernel<<<1024, 256, 0, stream>>>(Wq, Wk, Wv, Wo, Wb);

    dim3 gq(M_DIM / 128, C_DIM / 128, 3);
    gemm_qkv<<<gq, 256, 0, stream>>>(xb, Wb, Qh, Kh, Vt);

    if (ws_size >= NEED) {
        attn_split<<<2048, 128, 0, stream>>>(Qh, Kh, Vt, pO, pl);
        attn_merge<<<2048, 256, 0, stream>>>(pO, pl, attnb);
    } else {
        attn_fb<<<2048, 128, 0, stream>>>(Qh, Kh, Vt, attnb);
    }

    gemm_out<<<dim3(M_DIM / 128, C_DIM / 128), 256, 0, stream>>>(attnb, Wb + 3 * C_DIM * C_DIM, (float*)d_out);
}